// Round 1
// baseline (751.832 us; speedup 1.0000x reference)
//
#include <hip/hip_runtime.h>

// Problem constants (B=1 folded out)
constexpr int C  = 64;
constexpr int D  = 64;
constexpr int H  = 128;
constexpr int W  = 128;
constexpr int ZS = H * W;       // 16384   (z stride, elements)
constexpr int YS = W;           // 128     (y stride)
constexpr int CS = D * H * W;   // 1048576 (channel stride)

// One thread computes 4 consecutive x outputs for all 27 displacement taps.
// Channel loop is outermost; 27x4 accumulators live in VGPRs so each in1
// float4 is reused 27x and each in2 row value ~2x from registers.
__global__ __launch_bounds__(256)
void corr3d_kernel(const float* __restrict__ in1,
                   const float* __restrict__ in2,
                   float* __restrict__ out) {
    const int tx = threadIdx.x;           // 0..31 -> x0 = 4*tx
    const int ty = threadIdx.y;           // 0..7
    const int x0 = tx * 4;
    const int y  = blockIdx.x * 8 + ty;   // 0..127
    const int z  = blockIdx.y;            // 0..63

    float acc[27][4];
#pragma unroll
    for (int j = 0; j < 27; ++j) {
#pragma unroll
        for (int i = 0; i < 4; ++i) acc[j][i] = 0.0f;
    }

    const float* p1 = in1 + z * ZS + y * YS + x0;
    const bool xlo = (x0 > 0);      // x0-1 valid
    const bool xhi = (x0 < W - 4);  // x0+4 valid

    for (int c = 0; c < C; ++c) {
        const float4 a = *(const float4*)(p1 + c * CS);

#pragma unroll
        for (int dz = 0; dz < 3; ++dz) {
            const int zz = z + dz - 1;
            const bool zok = ((unsigned)zz < (unsigned)D);
#pragma unroll
            for (int dy = 0; dy < 3; ++dy) {
                const int yy = y + dy - 1;
                const bool ok = zok && ((unsigned)yy < (unsigned)H);

                float v0, v1, v2, v3, v4, v5;
                if (ok) {
                    const float* p = in2 + c * CS + zz * ZS + yy * YS + x0;
                    const float4 m = *(const float4*)p;
                    v1 = m.x; v2 = m.y; v3 = m.z; v4 = m.w;
                    v0 = xlo ? p[-1] : 0.0f;
                    v5 = xhi ? p[4]  : 0.0f;
                } else {
                    v0 = v1 = v2 = v3 = v4 = v5 = 0.0f;
                }

                const int jb = (dz * 3 + dy) * 3;
                // tap dx: out x index xi needs in2[x = xi + dx - 1] = v[i + dx]
                acc[jb + 0][0] += a.x * v0;
                acc[jb + 0][1] += a.y * v1;
                acc[jb + 0][2] += a.z * v2;
                acc[jb + 0][3] += a.w * v3;

                acc[jb + 1][0] += a.x * v1;
                acc[jb + 1][1] += a.y * v2;
                acc[jb + 1][2] += a.z * v3;
                acc[jb + 1][3] += a.w * v4;

                acc[jb + 2][0] += a.x * v2;
                acc[jb + 2][1] += a.y * v3;
                acc[jb + 2][2] += a.z * v4;
                acc[jb + 2][3] += a.w * v5;
            }
        }
    }

    const float s = 1.0f / (float)C;  // channel mean
    float* po = out + z * ZS + y * YS + x0;
#pragma unroll
    for (int j = 0; j < 27; ++j) {
        float4 o;
        o.x = acc[j][0] * s;
        o.y = acc[j][1] * s;
        o.z = acc[j][2] * s;
        o.w = acc[j][3] * s;
        *(float4*)(po + (size_t)j * CS) = o;
    }
}

extern "C" void kernel_launch(void* const* d_in, const int* in_sizes, int n_in,
                              void* d_out, int out_size, void* d_ws, size_t ws_size,
                              hipStream_t stream) {
    const float* in1 = (const float*)d_in[0];
    const float* in2 = (const float*)d_in[1];
    float* out = (float*)d_out;

    dim3 block(32, 8);        // 256 threads = 4 waves; wave = 2 y-rows
    dim3 grid(H / 8, D);      // (16 y-groups, 64 z)
    corr3d_kernel<<<grid, block, 0, stream>>>(in1, in2, out);
}